// Round 7
// baseline (1436.874 us; speedup 1.0000x reference)
//
#include <hip/hip_runtime.h>
#include <hip/hip_bf16.h>

#define N_PTS 400000
#define KOFF 27
#define AP 72  // LDS row pitch in ushorts: 144B, breaks pow2 bank aliasing

typedef __attribute__((ext_vector_type(8))) short short8;
typedef __attribute__((ext_vector_type(4))) float float4v;
typedef __attribute__((ext_vector_type(4))) unsigned int uint4v;  // native vec for nt stores

__device__ __forceinline__ unsigned short f2bf(float f) {
    union { float f; unsigned int u; } a; a.f = f;
    unsigned int u = a.u;
    unsigned int r = (u + 0x7FFFu + ((u >> 16) & 1u)) >> 16;
    return (unsigned short)r;
}

__device__ __forceinline__ float bf2f(unsigned short u) {
    union { unsigned int u; float f; } a; a.u = ((unsigned int)u) << 16;
    return a.f;
}

// ---- merged one-shot prep: cast features fp32->bf16 (blocks 0..24999),
// transpose+cast all 3 weight sets + zero stats (blocks 25000..25431) ----
__global__ void prep_kernel(const float* __restrict__ feat,
                            unsigned short* __restrict__ B0,
                            const float* __restrict__ W1,
                            const float* __restrict__ W2,
                            const float* __restrict__ W3,
                            unsigned short* __restrict__ Wt,
                            float* __restrict__ stats) {
    int b = blockIdx.x;
    int tid = threadIdx.x;
    if (b < 25000) {
        int i = b * 256 + tid;      // 6.4M float4 groups
        const float4* s4 = (const float4*)feat;
        float4 v = s4[i];
        ushort4 o;
        o.x = f2bf(v.x); o.y = f2bf(v.y); o.z = f2bf(v.z); o.w = f2bf(v.w);
        ((ushort4*)B0)[i] = o;
    } else {
        int i = (b - 25000) * 256 + tid;
        if (i < 384) stats[i] = 0.0f;
        if (i >= KOFF * 64 * 64) return;
        int k = i >> 12;
        int co = (i >> 6) & 63;
        int ci = i & 63;
        int src = (k << 12) + (ci << 6) + co;
        const int WS = KOFF * 4096;
        Wt[i] = f2bf(W1[src]);
        Wt[i + WS] = f2bf(W2[src]);
        Wt[i + 2 * WS] = f2bf(W3[src]);
    }
}

// BN+LeakyReLU(0.05) applied to 8 packed bf16 (one uint4) during staging.
__device__ __forceinline__ uint4 bn_u4(uint4 q, const float* S, const float* B, int c0) {
    union { uint4 q; unsigned short s[8]; } u;
    u.q = q;
    #pragma unroll
    for (int j = 0; j < 8; ++j) {
        float f = bf2f(u.s[j]) * S[c0 + j] + B[c0 + j];
        f = f >= 0.f ? f : 0.05f * f;
        u.s[j] = f2bf(f);
    }
    return u.q;
}

// ---- gather-GEMM + fused BN-stats reduction ----
// X: [N][64] bf16 (raw prev-conv output if APPLY_BN), nbr: [N][27] int,
// Wt: [27][64(co)][64(ci)] bf16.
// If APPLY_BN: BN(prev stats)+LeakyReLU(0.05) is applied to gathered rows
// in the staging path (global->reg->transform->LDS) -- deletes the
// standalone bnact kernels; VALU was 8% idle.
// Yout: bf16 raw (OUTBF=1, LDS-restaged full-line nt stores) or fp32 (OUTBF=0).
// stats: this conv's output sum/sumsq. pstats/pg/pb: previous layer BN params.
template<int OUTBF, int APPLY_BN>
__global__ __launch_bounds__(512, 8)
void conv_kernel(const unsigned short* __restrict__ X,
                 const int* __restrict__ nbr,
                 const unsigned short* __restrict__ Wt,
                 void* __restrict__ Yout,
                 float* __restrict__ stats,
                 const float* __restrict__ pstats,
                 const float* __restrict__ pg,
                 const float* __restrict__ pb) {
    __shared__ unsigned short lds_a[128 * AP];  // 18432 B (also C-restage scratch)
    __shared__ unsigned short lds_w[64 * AP];   //  9216 B (also stats scratch)
    __shared__ float bnS[64], bnB[64];
    const int tid = threadIdx.x;
    const int wave = tid >> 6;
    const int lane = tid & 63;
    const int quad = lane >> 4;
    const int l16 = lane & 15;
    const int p0 = blockIdx.x * 128;

    const int sr = tid >> 2;   // staging row 0..127 (4 threads/row)
    const int sq = tid & 3;    // 32B quarter of the 128B row
    const int wr = tid >> 3;   // W staging row (512 thr x 16B covers 8KB)
    const int wc = (tid & 7) << 3;

    if (APPLY_BN && tid < 64) {
        float m = pstats[tid] * (1.0f / N_PTS);
        float v = pstats[64 + tid] * (1.0f / N_PTS) - m * m;
        float rs = rsqrtf(v + 1e-4f);
        float sc = rs * pg[tid];
        bnS[tid] = sc;
        bnB[tid] = pb[tid] - m * sc;
    }
    // visibility of bnS/bnB covered by the k-loop's first __syncthreads()

    float4v acc[4];
    #pragma unroll
    for (int t = 0; t < 4; ++t) acc[t] = (float4v){0.f, 0.f, 0.f, 0.f};

    // prefetch pipeline: indices 2 ahead, rows/weights 1 ahead
    const long nb = (long)(p0 + sr) * KOFF;
    int gi = nbr[nb];
    int gin = nbr[nb + 1];
    uint4 a0, a1, w0;
    {
        const uint4* srcA = (const uint4*)(X + ((size_t)gi << 6)) + sq * 2;
        a0 = srcA[0];
        a1 = srcA[1];
        w0 = ((const uint4*)Wt)[tid];
    }

    for (int k = 0; k < KOFF; ++k) {
        __syncthreads();  // previous iteration's compute done reading LDS
        if (APPLY_BN) {
            *(uint4*)(lds_a + sr * AP + sq * 16) = bn_u4(a0, bnS, bnB, sq * 16);
            *(uint4*)(lds_a + sr * AP + sq * 16 + 8) = bn_u4(a1, bnS, bnB, sq * 16 + 8);
        } else {
            *(uint4*)(lds_a + sr * AP + sq * 16) = a0;
            *(uint4*)(lds_a + sr * AP + sq * 16 + 8) = a1;
        }
        *(uint4*)(lds_w + wr * AP + wc) = w0;
        if (k < KOFF - 1) {
            const uint4* srcA = (const uint4*)(X + ((size_t)gin << 6)) + sq * 2;
            a0 = srcA[0];
            a1 = srcA[1];
            w0 = ((const uint4*)(Wt + (((size_t)(k + 1)) << 12)))[tid];
            gin = (k < KOFF - 2) ? nbr[nb + k + 2] : 0;
        }
        __syncthreads();  // staged data visible
        const int abase = (wave * 16 + l16) * AP + quad * 8;
        #pragma unroll
        for (int ks = 0; ks < 2; ++ks) {
            short8 af = *(const short8*)(lds_a + abase + ks * 32);
            #pragma unroll
            for (int t = 0; t < 4; ++t) {
                short8 bf = *(const short8*)(lds_w + (t * 16 + l16) * AP + ks * 32 + quad * 8);
                acc[t] = __builtin_amdgcn_mfma_f32_16x16x32_bf16(af, bf, acc[t], 0, 0, 0);
            }
        }
    }

    // ---- epilogue: C write + fused BN stats ----
    float* red = (float*)lds_w;
    if (OUTBF) {
        // restage bf16 C in lds_a as contiguous [128][64] -> full-line nt stores
        __syncthreads();  // all waves done reading lds_a/lds_w
        {
            const int rl = wave * 16 + quad * 4;
            #pragma unroll
            for (int t = 0; t < 4; ++t)
                #pragma unroll
                for (int r = 0; r < 4; ++r)
                    lds_a[(rl + r) * 64 + t * 16 + l16] = f2bf(acc[t][r]);
        }
        if (tid < 128) red[tid] = 0.0f;
        __syncthreads();
        {
            const uint4v* lc = (const uint4v*)lds_a;
            uint4v* dst = (uint4v*)((unsigned short*)Yout + (size_t)p0 * 64);
            __builtin_nontemporal_store(lc[tid * 2], dst + tid * 2);
            __builtin_nontemporal_store(lc[tid * 2 + 1], dst + tid * 2 + 1);
        }
    } else {
        // fp32: direct 64B-chunk stores (full lines already)
        const int row_base = p0 + wave * 16 + quad * 4;
        #pragma unroll
        for (int t = 0; t < 4; ++t) {
            #pragma unroll
            for (int r = 0; r < 4; ++r) {
                size_t idx = (size_t)(row_base + r) * 64 + t * 16 + l16;
                __builtin_nontemporal_store(acc[t][r], (float*)Yout + idx);
            }
        }
        __syncthreads();  // done reading lds_w; reuse as fp32 scratch
        if (tid < 128) red[tid] = 0.0f;
        __syncthreads();
    }

    #pragma unroll
    for (int t = 0; t < 4; ++t) {
        float s = acc[t][0] + acc[t][1] + acc[t][2] + acc[t][3];
        float ss = acc[t][0] * acc[t][0] + acc[t][1] * acc[t][1] +
                   acc[t][2] * acc[t][2] + acc[t][3] * acc[t][3];
        s += __shfl_down(s, 32);
        s += __shfl_down(s, 16);
        ss += __shfl_down(ss, 32);
        ss += __shfl_down(ss, 16);
        if (lane < 16) {
            atomicAdd(&red[t * 16 + l16], s);
            atomicAdd(&red[64 + t * 16 + l16], ss);
        }
    }
    __syncthreads();
    if (tid < 128) atomicAdd(&stats[tid], red[tid]);
}

// ---- final: bn3 + residual (recomputed from raw Y1) + leakyrelu(0.333) ----
__global__ void bnact_final_kernel(float* __restrict__ Y,
                                   const float* __restrict__ stats3,
                                   const float* __restrict__ g3, const float* __restrict__ b3,
                                   const unsigned short* __restrict__ Y1raw,
                                   const float* __restrict__ stats1,
                                   const float* __restrict__ g1, const float* __restrict__ b1) {
    __shared__ float sc3[64], sh3[64], sc1[64], sh1[64];
    int tid = threadIdx.x;
    if (tid < 64) {
        float m = stats3[tid] * (1.0f / N_PTS);
        float v = stats3[64 + tid] * (1.0f / N_PTS) - m * m;
        float rs = rsqrtf(v + 1e-4f);
        float sc = rs * g3[tid];
        sc3[tid] = sc;
        sh3[tid] = b3[tid] - m * sc;
        m = stats1[tid] * (1.0f / N_PTS);
        v = stats1[64 + tid] * (1.0f / N_PTS) - m * m;
        rs = rsqrtf(v + 1e-4f);
        sc = rs * g1[tid];
        sc1[tid] = sc;
        sh1[tid] = b1[tid] - m * sc;
    }
    __syncthreads();
    int i = blockIdx.x * blockDim.x + tid;
    const int total = N_PTS * 16;
    if (i >= total) return;
    int cb = (i & 15) << 2;
    float4 y = ((const float4*)Y)[i];
    ushort4 r4 = ((const ushort4*)Y1raw)[i];
    float r0 = bf2f(r4.x) * sc1[cb] + sh1[cb];
    float r1 = bf2f(r4.y) * sc1[cb + 1] + sh1[cb + 1];
    float r2 = bf2f(r4.z) * sc1[cb + 2] + sh1[cb + 2];
    float r3 = bf2f(r4.w) * sc1[cb + 3] + sh1[cb + 3];
    r0 = r0 >= 0.f ? r0 : 0.05f * r0;
    r1 = r1 >= 0.f ? r1 : 0.05f * r1;
    r2 = r2 >= 0.f ? r2 : 0.05f * r2;
    r3 = r3 >= 0.f ? r3 : 0.05f * r3;
    float o0 = y.x * sc3[cb] + sh3[cb] + r0;
    float o1 = y.y * sc3[cb + 1] + sh3[cb + 1] + r1;
    float o2 = y.z * sc3[cb + 2] + sh3[cb + 2] + r2;
    float o3 = y.w * sc3[cb + 3] + sh3[cb + 3] + r3;
    o0 = o0 >= 0.f ? o0 : 0.333f * o0;
    o1 = o1 >= 0.f ? o1 : 0.333f * o1;
    o2 = o2 >= 0.f ? o2 : 0.333f * o2;
    o3 = o3 >= 0.f ? o3 : 0.333f * o3;
    float4 o; o.x = o0; o.y = o1; o.z = o2; o.w = o3;
    ((float4*)Y)[i] = o;
}

extern "C" void kernel_launch(void* const* d_in, const int* in_sizes, int n_in,
                              void* d_out, int out_size, void* d_ws, size_t ws_size,
                              hipStream_t stream) {
    const float* feat = (const float*)d_in[0];
    const int* nbr = (const int*)d_in[1];
    const float* W1 = (const float*)d_in[2];
    const float* g1 = (const float*)d_in[3];
    const float* b1 = (const float*)d_in[4];
    const float* W2 = (const float*)d_in[5];
    const float* g2 = (const float*)d_in[6];
    const float* b2 = (const float*)d_in[7];
    const float* W3 = (const float*)d_in[8];
    const float* g3 = (const float*)d_in[9];
    const float* b3 = (const float*)d_in[10];
    float* Y = (float*)d_out;

    char* ws = (char*)d_ws;
    const size_t BF_BYTES = (size_t)N_PTS * 64 * 2;  // 51.2 MB
    unsigned short* B0 = (unsigned short*)ws;            // feat bf16, then Y2raw
    unsigned short* B1 = (unsigned short*)(ws + BF_BYTES);  // Y1raw (kept for residual)
    unsigned short* Wt = (unsigned short*)(ws + 2 * BF_BYTES);
    float* stats = (float*)(ws + 2 * BF_BYTES + (size_t)3 * KOFF * 4096 * 2);

    const int WSTRIDE = KOFF * 4096;  // 110592

    // merged cast + weight-prep (one launch)
    prep_kernel<<<25432, 256, 0, stream>>>(feat, B0, W1, W2, W3, Wt, stats);

    // conv1: raw gather (features), raw bf16 out -> B1 (Y1raw)
    conv_kernel<1, 0><<<N_PTS / 128, 512, 0, stream>>>(
        B0, nbr, Wt, (void*)B1, stats, stats, g1, b1);
    // conv2: gather Y1raw with BN1+lrelu applied in staging; raw bf16 out -> B0
    conv_kernel<1, 1><<<N_PTS / 128, 512, 0, stream>>>(
        B1, nbr, Wt + WSTRIDE, (void*)B0, stats + 128, stats, g1, b1);
    // conv3: gather Y2raw with BN2+lrelu applied in staging; fp32 out -> d_out
    conv_kernel<0, 1><<<N_PTS / 128, 512, 0, stream>>>(
        B0, nbr, Wt + 2 * WSTRIDE, (void*)Y, stats + 256, stats + 128, g2, b2);
    // final: BN3 + residual(recomputed from Y1raw via BN1+lrelu) + lrelu(0.333)
    bnact_final_kernel<<<25000, 256, 0, stream>>>(
        Y, stats + 256, g3, b3, B1, stats, g1, b1);
}

// Round 8
// 1000.156 us; speedup vs baseline: 1.4366x; 1.4366x over previous
//
#include <hip/hip_runtime.h>
#include <hip/hip_bf16.h>

#define N_PTS 400000
#define KOFF 27
#define AP 72  // LDS row pitch in ushorts: 144B, breaks pow2 bank aliasing

typedef __attribute__((ext_vector_type(8))) short short8;
typedef __attribute__((ext_vector_type(4))) float float4v;

__device__ __forceinline__ unsigned short f2bf(float f) {
    union { float f; unsigned int u; } a; a.f = f;
    unsigned int u = a.u;
    unsigned int r = (u + 0x7FFFu + ((u >> 16) & 1u)) >> 16;
    return (unsigned short)r;
}

__device__ __forceinline__ float bf2f(unsigned short u) {
    union { unsigned int u; float f; } a; a.u = ((unsigned int)u) << 16;
    return a.f;
}

// ---- merged one-shot prep: cast features fp32->bf16 (blocks 0..24999),
// transpose+cast all 3 weight sets + zero stats (blocks 25000..25431) ----
__global__ void prep_kernel(const float* __restrict__ feat,
                            unsigned short* __restrict__ B0,
                            const float* __restrict__ W1,
                            const float* __restrict__ W2,
                            const float* __restrict__ W3,
                            unsigned short* __restrict__ Wt,
                            float* __restrict__ stats) {
    int b = blockIdx.x;
    int tid = threadIdx.x;
    if (b < 25000) {
        int i = b * 256 + tid;      // 6.4M float4 groups
        const float4* s4 = (const float4*)feat;
        float4 v = s4[i];
        ushort4 o;
        o.x = f2bf(v.x); o.y = f2bf(v.y); o.z = f2bf(v.z); o.w = f2bf(v.w);
        ((ushort4*)B0)[i] = o;
    } else {
        int i = (b - 25000) * 256 + tid;
        if (i < 384) stats[i] = 0.0f;
        if (i >= KOFF * 64 * 64) return;
        int k = i >> 12;
        int co = (i >> 6) & 63;
        int ci = i & 63;
        int src = (k << 12) + (ci << 6) + co;
        const int WS = KOFF * 4096;
        Wt[i] = f2bf(W1[src]);
        Wt[i + WS] = f2bf(W2[src]);
        Wt[i + 2 * WS] = f2bf(W3[src]);
    }
}

// ---- gather-GEMM + fused BN-stats reduction ----
// X: [N][64] bf16, nbr: [N][27] int, Wt: [27][64(co)][64(ci)] bf16
// Y: [N][64] fp32, stats: [128] fp32 (sum, sumsq) pre-zeroed
// Block: 512 threads (8 waves), M-tile = 128 points; register prefetch dbuf.
// launch_bounds(512,6): 3 blocks/CU — measured lowest FETCH (728 MB) and
// best total; 4 blocks/CU raised FETCH +38 MB for 0 time gain (round 4).
__global__ __launch_bounds__(512, 6)
void conv_kernel(const unsigned short* __restrict__ X,
                 const int* __restrict__ nbr,
                 const unsigned short* __restrict__ Wt,
                 float* __restrict__ Y,
                 float* __restrict__ stats) {
    __shared__ unsigned short lds_a[128 * AP];  // 18432 B
    __shared__ unsigned short lds_w[64 * AP];   //  9216 B
    const int tid = threadIdx.x;
    const int wave = tid >> 6;
    const int lane = tid & 63;
    const int quad = lane >> 4;
    const int l16 = lane & 15;
    const int p0 = blockIdx.x * 128;

    const int sr = tid >> 2;   // staging row 0..127 (4 threads/row)
    const int sq = tid & 3;    // 32B quarter of the 128B row
    const int wr = tid >> 3;   // W staging row (512 thr x 16B covers 8KB)
    const int wc = (tid & 7) << 3;

    float4v acc[4];
    #pragma unroll
    for (int t = 0; t < 4; ++t) acc[t] = (float4v){0.f, 0.f, 0.f, 0.f};

    // prefetch pipeline: indices 2 ahead, rows/weights 1 ahead
    const long nb = (long)(p0 + sr) * KOFF;
    int gi = nbr[nb];
    int gin = nbr[nb + 1];
    uint4 a0, a1, w0;
    {
        const uint4* srcA = (const uint4*)(X + ((size_t)gi << 6)) + sq * 2;
        a0 = srcA[0];
        a1 = srcA[1];
        w0 = ((const uint4*)Wt)[tid];
    }

    for (int k = 0; k < KOFF; ++k) {
        __syncthreads();  // previous iteration's compute done reading LDS
        *(uint4*)(lds_a + sr * AP + sq * 16) = a0;
        *(uint4*)(lds_a + sr * AP + sq * 16 + 8) = a1;
        *(uint4*)(lds_w + wr * AP + wc) = w0;
        if (k < KOFF - 1) {
            const uint4* srcA = (const uint4*)(X + ((size_t)gin << 6)) + sq * 2;
            a0 = srcA[0];
            a1 = srcA[1];
            w0 = ((const uint4*)(Wt + (((size_t)(k + 1)) << 12)))[tid];
            gin = (k < KOFF - 2) ? nbr[nb + k + 2] : 0;
        }
        __syncthreads();  // staged data visible
        const int abase = (wave * 16 + l16) * AP + quad * 8;
        #pragma unroll
        for (int ks = 0; ks < 2; ++ks) {
            short8 af = *(const short8*)(lds_a + abase + ks * 32);
            #pragma unroll
            for (int t = 0; t < 4; ++t) {
                short8 bf = *(const short8*)(lds_w + (t * 16 + l16) * AP + ks * 32 + quad * 8);
                acc[t] = __builtin_amdgcn_mfma_f32_16x16x32_bf16(af, bf, acc[t], 0, 0, 0);
            }
        }
    }

    // write C: row = p0 + wave*16 + quad*4 + r, col = t*16 + l16
    const int row_base = p0 + wave * 16 + quad * 4;
    #pragma unroll
    for (int t = 0; t < 4; ++t) {
        #pragma unroll
        for (int r = 0; r < 4; ++r) {
            Y[(size_t)(row_base + r) * 64 + t * 16 + l16] = acc[t][r];
        }
    }

    // fused BN stats: per-lane over 4 rows -> shuffle across quads -> LDS -> 1 atomic/block
    __syncthreads();  // done reading lds_w; reuse as fp32 scratch
    float* red = (float*)lds_w;
    if (tid < 128) red[tid] = 0.0f;
    __syncthreads();
    #pragma unroll
    for (int t = 0; t < 4; ++t) {
        float s = acc[t][0] + acc[t][1] + acc[t][2] + acc[t][3];
        float ss = acc[t][0] * acc[t][0] + acc[t][1] * acc[t][1] +
                   acc[t][2] * acc[t][2] + acc[t][3] * acc[t][3];
        s += __shfl_down(s, 32);
        s += __shfl_down(s, 16);
        ss += __shfl_down(ss, 32);
        ss += __shfl_down(ss, 16);
        if (lane < 16) {
            atomicAdd(&red[t * 16 + l16], s);
            atomicAdd(&red[64 + t * 16 + l16], ss);
        }
    }
    __syncthreads();
    if (tid < 128) atomicAdd(&stats[tid], red[tid]);
}

// ---- bn + leakyrelu -> bf16 output (input to next conv) ----
__global__ void bnact_kernel(const float* __restrict__ Y, const float* __restrict__ stats,
                             const float* __restrict__ g, const float* __restrict__ b,
                             unsigned short* __restrict__ Xb, float slope) {
    __shared__ float scale[64], shift[64];
    int tid = threadIdx.x;
    if (tid < 64) {
        float m = stats[tid] * (1.0f / N_PTS);
        float v = stats[64 + tid] * (1.0f / N_PTS) - m * m;
        float rs = rsqrtf(v + 1e-4f);
        float sc = rs * g[tid];
        scale[tid] = sc;
        shift[tid] = b[tid] - m * sc;
    }
    __syncthreads();
    int i = blockIdx.x * blockDim.x + tid;
    const int total = N_PTS * 16;
    if (i >= total) return;
    int cb = (i & 15) << 2;
    float4 y = ((const float4*)Y)[i];
    float o0 = y.x * scale[cb] + shift[cb];
    float o1 = y.y * scale[cb + 1] + shift[cb + 1];
    float o2 = y.z * scale[cb + 2] + shift[cb + 2];
    float o3 = y.w * scale[cb + 3] + shift[cb + 3];
    o0 = o0 >= 0.f ? o0 : slope * o0;
    o1 = o1 >= 0.f ? o1 : slope * o1;
    o2 = o2 >= 0.f ? o2 : slope * o2;
    o3 = o3 >= 0.f ? o3 : slope * o3;
    ushort4 o;
    o.x = f2bf(o0); o.y = f2bf(o1); o.z = f2bf(o2); o.w = f2bf(o3);
    ((ushort4*)Xb)[i] = o;
}

// ---- final: bn3 + residual + leakyrelu(0.333) -> fp32 d_out (in place over Y) ----
__global__ void bnact_final_kernel(float* __restrict__ Y, const float* __restrict__ stats,
                                   const float* __restrict__ g, const float* __restrict__ b,
                                   const unsigned short* __restrict__ res) {
    __shared__ float scale[64], shift[64];
    int tid = threadIdx.x;
    if (tid < 64) {
        float m = stats[tid] * (1.0f / N_PTS);
        float v = stats[64 + tid] * (1.0f / N_PTS) - m * m;
        float rs = rsqrtf(v + 1e-4f);
        float sc = rs * g[tid];
        scale[tid] = sc;
        shift[tid] = b[tid] - m * sc;
    }
    __syncthreads();
    int i = blockIdx.x * blockDim.x + tid;
    const int total = N_PTS * 16;
    if (i >= total) return;
    int cb = (i & 15) << 2;
    float4 y = ((const float4*)Y)[i];
    ushort4 r4 = ((const ushort4*)res)[i];
    float o0 = y.x * scale[cb] + shift[cb] + bf2f(r4.x);
    float o1 = y.y * scale[cb + 1] + shift[cb + 1] + bf2f(r4.y);
    float o2 = y.z * scale[cb + 2] + shift[cb + 2] + bf2f(r4.z);
    float o3 = y.w * scale[cb + 3] + shift[cb + 3] + bf2f(r4.w);
    o0 = o0 >= 0.f ? o0 : 0.333f * o0;
    o1 = o1 >= 0.f ? o1 : 0.333f * o1;
    o2 = o2 >= 0.f ? o2 : 0.333f * o2;
    o3 = o3 >= 0.f ? o3 : 0.333f * o3;
    float4 o; o.x = o0; o.y = o1; o.z = o2; o.w = o3;
    ((float4*)Y)[i] = o;
}

extern "C" void kernel_launch(void* const* d_in, const int* in_sizes, int n_in,
                              void* d_out, int out_size, void* d_ws, size_t ws_size,
                              hipStream_t stream) {
    const float* feat = (const float*)d_in[0];
    const int* nbr = (const int*)d_in[1];
    const float* W1 = (const float*)d_in[2];
    const float* g1 = (const float*)d_in[3];
    const float* b1 = (const float*)d_in[4];
    const float* W2 = (const float*)d_in[5];
    const float* g2 = (const float*)d_in[6];
    const float* b2 = (const float*)d_in[7];
    const float* W3 = (const float*)d_in[8];
    const float* g3 = (const float*)d_in[9];
    const float* b3 = (const float*)d_in[10];
    float* Y = (float*)d_out;

    char* ws = (char*)d_ws;
    const size_t BF_BYTES = (size_t)N_PTS * 64 * 2;  // 51.2 MB
    unsigned short* B0 = (unsigned short*)ws;
    unsigned short* B1 = (unsigned short*)(ws + BF_BYTES);
    unsigned short* Wt = (unsigned short*)(ws + 2 * BF_BYTES);
    float* stats = (float*)(ws + 2 * BF_BYTES + (size_t)3 * KOFF * 4096 * 2);

    const int WSTRIDE = KOFF * 4096;  // 110592

    // merged cast + weight-prep (one launch)
    prep_kernel<<<25432, 256, 0, stream>>>(feat, B0, W1, W2, W3, Wt, stats);

    // block 1
    conv_kernel<<<N_PTS / 128, 512, 0, stream>>>(B0, nbr, Wt, Y, stats);
    bnact_kernel<<<25000, 256, 0, stream>>>(Y, stats, g1, b1, B1, 0.05f);
    // block 2
    conv_kernel<<<N_PTS / 128, 512, 0, stream>>>(B1, nbr, Wt + WSTRIDE, Y, stats + 128);
    bnact_kernel<<<25000, 256, 0, stream>>>(Y, stats + 128, g2, b2, B0, 0.05f);
    // block 3 + residual
    conv_kernel<<<N_PTS / 128, 512, 0, stream>>>(B0, nbr, Wt + 2 * WSTRIDE, Y, stats + 256);
    bnact_final_kernel<<<25000, 256, 0, stream>>>(Y, stats + 256, g3, b3, B1);
}

// Round 9
// 975.427 us; speedup vs baseline: 1.4731x; 1.0254x over previous
//
#include <hip/hip_runtime.h>
#include <hip/hip_bf16.h>

#define N_PTS 400000
#define KOFF 27
#define AP 72  // LDS row pitch in ushorts: 144B, breaks pow2 bank aliasing

typedef __attribute__((ext_vector_type(8))) short short8;
typedef __attribute__((ext_vector_type(4))) float float4v;
typedef __attribute__((ext_vector_type(4))) unsigned int uint4v;

__device__ __forceinline__ unsigned short f2bf(float f) {
    union { float f; unsigned int u; } a; a.f = f;
    unsigned int u = a.u;
    unsigned int r = (u + 0x7FFFu + ((u >> 16) & 1u)) >> 16;
    return (unsigned short)r;
}

__device__ __forceinline__ float bf2f(unsigned short u) {
    union { unsigned int u; float f; } a; a.u = ((unsigned int)u) << 16;
    return a.f;
}

// ---- merged one-shot prep: cast features fp32->bf16 (blocks 0..24999),
// transpose+cast all 3 weight sets + zero stats (blocks 25000..25431) ----
__global__ void prep_kernel(const float* __restrict__ feat,
                            unsigned short* __restrict__ B0,
                            const float* __restrict__ W1,
                            const float* __restrict__ W2,
                            const float* __restrict__ W3,
                            unsigned short* __restrict__ Wt,
                            float* __restrict__ stats) {
    int b = blockIdx.x;
    int tid = threadIdx.x;
    if (b < 25000) {
        int i = b * 256 + tid;      // 6.4M float4 groups
        const float4* s4 = (const float4*)feat;
        float4 v = s4[i];
        ushort4 o;
        o.x = f2bf(v.x); o.y = f2bf(v.y); o.z = f2bf(v.z); o.w = f2bf(v.w);
        ((ushort4*)B0)[i] = o;
    } else {
        int i = (b - 25000) * 256 + tid;
        if (i < 384) stats[i] = 0.0f;
        if (i >= KOFF * 64 * 64) return;
        int k = i >> 12;
        int co = (i >> 6) & 63;
        int ci = i & 63;
        int src = (k << 12) + (ci << 6) + co;
        const int WS = KOFF * 4096;
        Wt[i] = f2bf(W1[src]);
        Wt[i + WS] = f2bf(W2[src]);
        Wt[i + 2 * WS] = f2bf(W3[src]);
    }
}

// ---- gather-GEMM + fused BN-stats reduction ----
// X: [N][64] bf16, nbr: [N][27] int, Wt: [27][64(co)][64(ci)] bf16
// Yout: bf16 (OUTBF=1, LDS-restaged full-line PLAIN stores) or fp32 (OUTBF=0)
// stats: [128] fp32 (sum, sumsq) pre-zeroed
// Block: 512 threads (8 waves), M-tile = 128 points; register prefetch dbuf.
// launch_bounds(512,6): 3 blocks/CU — measured best (round 4: 4 blocks/CU
// raised FETCH +38MB for 0 time gain). NO nontemporal anywhere (round 5:
// nt caused sector write-amplification; round 7: nt poisoned reuse).
template<int OUTBF>
__global__ __launch_bounds__(512, 6)
void conv_kernel(const unsigned short* __restrict__ X,
                 const int* __restrict__ nbr,
                 const unsigned short* __restrict__ Wt,
                 void* __restrict__ Yout,
                 float* __restrict__ stats) {
    __shared__ unsigned short lds_a[128 * AP];  // 18432 B (also C-restage scratch)
    __shared__ unsigned short lds_w[64 * AP];   //  9216 B (also stats scratch)
    const int tid = threadIdx.x;
    const int wave = tid >> 6;
    const int lane = tid & 63;
    const int quad = lane >> 4;
    const int l16 = lane & 15;
    const int p0 = blockIdx.x * 128;

    const int sr = tid >> 2;   // staging row 0..127 (4 threads/row)
    const int sq = tid & 3;    // 32B quarter of the 128B row
    const int wr = tid >> 3;   // W staging row (512 thr x 16B covers 8KB)
    const int wc = (tid & 7) << 3;

    float4v acc[4];
    #pragma unroll
    for (int t = 0; t < 4; ++t) acc[t] = (float4v){0.f, 0.f, 0.f, 0.f};

    // prefetch pipeline: indices 2 ahead, rows/weights 1 ahead
    const long nb = (long)(p0 + sr) * KOFF;
    int gi = nbr[nb];
    int gin = nbr[nb + 1];
    uint4 a0, a1, w0;
    {
        const uint4* srcA = (const uint4*)(X + ((size_t)gi << 6)) + sq * 2;
        a0 = srcA[0];
        a1 = srcA[1];
        w0 = ((const uint4*)Wt)[tid];
    }

    for (int k = 0; k < KOFF; ++k) {
        __syncthreads();  // previous iteration's compute done reading LDS
        *(uint4*)(lds_a + sr * AP + sq * 16) = a0;
        *(uint4*)(lds_a + sr * AP + sq * 16 + 8) = a1;
        *(uint4*)(lds_w + wr * AP + wc) = w0;
        if (k < KOFF - 1) {
            const uint4* srcA = (const uint4*)(X + ((size_t)gin << 6)) + sq * 2;
            a0 = srcA[0];
            a1 = srcA[1];
            w0 = ((const uint4*)(Wt + (((size_t)(k + 1)) << 12)))[tid];
            gin = (k < KOFF - 2) ? nbr[nb + k + 2] : 0;
        }
        __syncthreads();  // staged data visible
        const int abase = (wave * 16 + l16) * AP + quad * 8;
        #pragma unroll
        for (int ks = 0; ks < 2; ++ks) {
            short8 af = *(const short8*)(lds_a + abase + ks * 32);
            #pragma unroll
            for (int t = 0; t < 4; ++t) {
                short8 bf = *(const short8*)(lds_w + (t * 16 + l16) * AP + ks * 32 + quad * 8);
                acc[t] = __builtin_amdgcn_mfma_f32_16x16x32_bf16(af, bf, acc[t], 0, 0, 0);
            }
        }
    }

    // ---- epilogue: C write + fused BN stats ----
    float* red = (float*)lds_w;
    if (OUTBF) {
        // restage bf16 C in lds_a as contiguous [128][64] -> full-line stores
        __syncthreads();  // all waves done reading lds_a/lds_w
        {
            const int rl = wave * 16 + quad * 4;
            #pragma unroll
            for (int t = 0; t < 4; ++t)
                #pragma unroll
                for (int r = 0; r < 4; ++r)
                    lds_a[(rl + r) * 64 + t * 16 + l16] = f2bf(acc[t][r]);
        }
        if (tid < 128) red[tid] = 0.0f;
        __syncthreads();
        {
            const uint4v* lc = (const uint4v*)lds_a;
            uint4v* dst = (uint4v*)((unsigned short*)Yout + (size_t)p0 * 64);
            dst[tid * 2] = lc[tid * 2];
            dst[tid * 2 + 1] = lc[tid * 2 + 1];
        }
    } else {
        // fp32: direct stores (16 lanes x 4B = 64B contiguous chunks)
        const int row_base = p0 + wave * 16 + quad * 4;
        #pragma unroll
        for (int t = 0; t < 4; ++t) {
            #pragma unroll
            for (int r = 0; r < 4; ++r) {
                ((float*)Yout)[(size_t)(row_base + r) * 64 + t * 16 + l16] = acc[t][r];
            }
        }
        __syncthreads();  // done reading lds_w; reuse as fp32 scratch
        if (tid < 128) red[tid] = 0.0f;
        __syncthreads();
    }

    #pragma unroll
    for (int t = 0; t < 4; ++t) {
        float s = acc[t][0] + acc[t][1] + acc[t][2] + acc[t][3];
        float ss = acc[t][0] * acc[t][0] + acc[t][1] * acc[t][1] +
                   acc[t][2] * acc[t][2] + acc[t][3] * acc[t][3];
        s += __shfl_down(s, 32);
        s += __shfl_down(s, 16);
        ss += __shfl_down(ss, 32);
        ss += __shfl_down(ss, 16);
        if (lane < 16) {
            atomicAdd(&red[t * 16 + l16], s);
            atomicAdd(&red[64 + t * 16 + l16], ss);
        }
    }
    __syncthreads();
    if (tid < 128) atomicAdd(&stats[tid], red[tid]);
}

// ---- bn + leakyrelu on bf16 Y -> bf16 output (input to next conv) ----
__global__ void bnact_kernel(const unsigned short* __restrict__ Yb,
                             const float* __restrict__ stats,
                             const float* __restrict__ g, const float* __restrict__ b,
                             unsigned short* __restrict__ Xb, float slope) {
    __shared__ float scale[64], shift[64];
    int tid = threadIdx.x;
    if (tid < 64) {
        float m = stats[tid] * (1.0f / N_PTS);
        float v = stats[64 + tid] * (1.0f / N_PTS) - m * m;
        float rs = rsqrtf(v + 1e-4f);
        float sc = rs * g[tid];
        scale[tid] = sc;
        shift[tid] = b[tid] - m * sc;
    }
    __syncthreads();
    int i = blockIdx.x * blockDim.x + tid;
    const int total = N_PTS * 16;
    if (i >= total) return;
    int cb = (i & 15) << 2;
    ushort4 y4 = ((const ushort4*)Yb)[i];
    float o0 = bf2f(y4.x) * scale[cb] + shift[cb];
    float o1 = bf2f(y4.y) * scale[cb + 1] + shift[cb + 1];
    float o2 = bf2f(y4.z) * scale[cb + 2] + shift[cb + 2];
    float o3 = bf2f(y4.w) * scale[cb + 3] + shift[cb + 3];
    o0 = o0 >= 0.f ? o0 : slope * o0;
    o1 = o1 >= 0.f ? o1 : slope * o1;
    o2 = o2 >= 0.f ? o2 : slope * o2;
    o3 = o3 >= 0.f ? o3 : slope * o3;
    ushort4 o;
    o.x = f2bf(o0); o.y = f2bf(o1); o.z = f2bf(o2); o.w = f2bf(o3);
    ((ushort4*)Xb)[i] = o;
}

// ---- final: bn3 + residual + leakyrelu(0.333) -> fp32 d_out (in place over Y) ----
__global__ void bnact_final_kernel(float* __restrict__ Y, const float* __restrict__ stats,
                                   const float* __restrict__ g, const float* __restrict__ b,
                                   const unsigned short* __restrict__ res) {
    __shared__ float scale[64], shift[64];
    int tid = threadIdx.x;
    if (tid < 64) {
        float m = stats[tid] * (1.0f / N_PTS);
        float v = stats[64 + tid] * (1.0f / N_PTS) - m * m;
        float rs = rsqrtf(v + 1e-4f);
        float sc = rs * g[tid];
        scale[tid] = sc;
        shift[tid] = b[tid] - m * sc;
    }
    __syncthreads();
    int i = blockIdx.x * blockDim.x + tid;
    const int total = N_PTS * 16;
    if (i >= total) return;
    int cb = (i & 15) << 2;
    float4 y = ((const float4*)Y)[i];
    ushort4 r4 = ((const ushort4*)res)[i];
    float o0 = y.x * scale[cb] + shift[cb] + bf2f(r4.x);
    float o1 = y.y * scale[cb + 1] + shift[cb + 1] + bf2f(r4.y);
    float o2 = y.z * scale[cb + 2] + shift[cb + 2] + bf2f(r4.z);
    float o3 = y.w * scale[cb + 3] + shift[cb + 3] + bf2f(r4.w);
    o0 = o0 >= 0.f ? o0 : 0.333f * o0;
    o1 = o1 >= 0.f ? o1 : 0.333f * o1;
    o2 = o2 >= 0.f ? o2 : 0.333f * o2;
    o3 = o3 >= 0.f ? o3 : 0.333f * o3;
    float4 o; o.x = o0; o.y = o1; o.z = o2; o.w = o3;
    ((float4*)Y)[i] = o;
}

extern "C" void kernel_launch(void* const* d_in, const int* in_sizes, int n_in,
                              void* d_out, int out_size, void* d_ws, size_t ws_size,
                              hipStream_t stream) {
    const float* feat = (const float*)d_in[0];
    const int* nbr = (const int*)d_in[1];
    const float* W1 = (const float*)d_in[2];
    const float* g1 = (const float*)d_in[3];
    const float* b1 = (const float*)d_in[4];
    const float* W2 = (const float*)d_in[5];
    const float* g2 = (const float*)d_in[6];
    const float* b2 = (const float*)d_in[7];
    const float* W3 = (const float*)d_in[8];
    const float* g3 = (const float*)d_in[9];
    const float* b3 = (const float*)d_in[10];
    float* Y = (float*)d_out;
    // bf16 Y for conv1/conv2 lives in d_out's lower half (fp32 Y unused
    // until conv3, which then overwrites the whole buffer; bnact has
    // consumed Ybf by then).
    unsigned short* Ybf = (unsigned short*)d_out;

    char* ws = (char*)d_ws;
    const size_t BF_BYTES = (size_t)N_PTS * 64 * 2;  // 51.2 MB
    unsigned short* B0 = (unsigned short*)ws;            // feat bf16, later bnact2 out
    unsigned short* B1 = (unsigned short*)(ws + BF_BYTES);  // bnact1 out (residual)
    unsigned short* Wt = (unsigned short*)(ws + 2 * BF_BYTES);
    float* stats = (float*)(ws + 2 * BF_BYTES + (size_t)3 * KOFF * 4096 * 2);

    const int WSTRIDE = KOFF * 4096;  // 110592

    // merged cast + weight-prep (one launch)
    prep_kernel<<<25432, 256, 0, stream>>>(feat, B0, W1, W2, W3, Wt, stats);

    // block 1: conv (bf16 Y) -> bnact -> B1
    conv_kernel<1><<<N_PTS / 128, 512, 0, stream>>>(B0, nbr, Wt, (void*)Ybf, stats);
    bnact_kernel<<<25000, 256, 0, stream>>>(Ybf, stats, g1, b1, B1, 0.05f);
    // block 2: conv (bf16 Y) -> bnact -> B0
    conv_kernel<1><<<N_PTS / 128, 512, 0, stream>>>(B1, nbr, Wt + WSTRIDE, (void*)Ybf, stats + 128);
    bnact_kernel<<<25000, 256, 0, stream>>>(Ybf, stats + 128, g2, b2, B0, 0.05f);
    // block 3: conv (fp32 Y in d_out) + residual
    conv_kernel<0><<<N_PTS / 128, 512, 0, stream>>>(B0, nbr, Wt + 2 * WSTRIDE, (void*)Y, stats + 256);
    bnact_final_kernel<<<25000, 256, 0, stream>>>(Y, stats + 256, g3, b3, B1);
}